// Round 16
// baseline (99.903 us; speedup 1.0000x reference)
//
#include <hip/hip_runtime.h>
#include <math.h>

#define BB 32
#define NN 64
#define PP 4
#define HH 300

#define NKK 10    // edge reduction tiles: ceil(300/32)
#define NCT 19    // node output col-tiles of 16: ceil(300/16)
#define NCTE 20   // edge col-tiles PADDED to even (tile 19 = zeros)
#define NPAIR 10  // edge ct-pair iterations
#define NKK2 38   // node reduction tiles: ceil(1200/32)
#define CHK 10    // node kk chunk size (4 chunks cover 38)

#define NODE_BLOCKS (BB * 4)          // 128
#define EDGE_BLOCKS (BB * NN)         // 2048 (one m per block now)
#define ASTR 344                      // A LDS row stride in fp16 (688 B):
                                      // 16B-aligned rows, 172%32=12 -> 2-way banks

typedef float    f32x4 __attribute__((ext_vector_type(4)));
typedef _Float16 f16x8 __attribute__((ext_vector_type(8)));
typedef _Float16 f16x4 __attribute__((ext_vector_type(4)));

__device__ __forceinline__ float eluf(float x) {
    return x > 0.0f ? x : (__expf(x) - 1.0f);
}

// ---------------------------------------------------------------------------
// Merged W-prep (round 15): edge fragments (NCTE=20) + node fragments (NCT=19).
// tile (kk, ct): lane l, elem j holds W[h][k], h = kk*32 + (l>>4)*8 + j,
// k = ct*16 + (l&15); zero-padded outside valid range.
// ---------------------------------------------------------------------------
extern "C" __global__ __launch_bounds__(64)
void wprep_kernel(const float* __restrict__ w_edge,
                  const float* __restrict__ w_np,
                  _Float16* __restrict__ w_hi,
                  _Float16* __restrict__ w2_hi)
{
    const int lane = (int)threadIdx.x;
    int bid = (int)blockIdx.x;
    if (bid < NKK * NCTE) {
        const int kk = bid / NCTE, ct = bid % NCTE;
        const int h0 = kk * 32 + (lane >> 4) * 8;
        const int k  = ct * 16 + (lane & 15);
        const size_t base = ((size_t)bid * 64 + lane) * 8;
#pragma unroll
        for (int j = 0; j < 8; ++j) {
            int h = h0 + j;
            float v = (h < HH && k < HH) ? w_edge[h * HH + k] : 0.f;
            w_hi[base + j] = (_Float16)v;
        }
    } else {
        bid -= NKK * NCTE;
        const int kk = bid / NCT, ct = bid % NCT;
        const int h0 = kk * 32 + (lane >> 4) * 8;
        const int k  = ct * 16 + (lane & 15);
        const size_t base = ((size_t)bid * 64 + lane) * 8;
#pragma unroll
        for (int j = 0; j < 8; ++j) {
            int h = h0 + j;
            float v = (h < PP * HH && k < HH) ? w_np[(size_t)h * HH + k] : 0.f;
            w2_hi[base + j] = (_Float16)v;
        }
    }
}

// ---------------------------------------------------------------------------
// FUSED edge + node kernel. ROUND-16 CHANGE (edge path only): COALESCED A
// STAGING. The fill kernels prove 7 TB/s at 10% occupancy with contiguous
// access; our scattered A-read (16B/lane at 1200B row stride) ran at 0.9
// TB/s and set the kernel time (dur ~= FETCH/0.9TB/s). Now: each edge
// block streams its fully-CONTIGUOUS 76.8 KB A-slice with coalesced
// float4 loads -> cvt fp16 -> LDS (stride 344 fp16: rows 16B-aligned,
// ~2-way banks) -> per-wave fragment ds_read_b128 (once). One m per
// block, 4 waves x 16 rows, ct-pair chains; B staging = round 12's.
// Node path byte-identical to round 15.
// ---------------------------------------------------------------------------
extern "C" __global__ __launch_bounds__(256)
void fused_kernel(const float* __restrict__ edge_attr,
                  const float* __restrict__ node_attr,
                  const float* __restrict__ instr,
                  const float* __restrict__ dist,
                  const float* __restrict__ sim,
                  const float* __restrict__ node_mask,
                  const _Float16* __restrict__ w_hi,
                  const _Float16* __restrict__ w2_hi,
                  const float* __restrict__ w_rel,
                  const float* __restrict__ w_state,
                  float* __restrict__ rel_logits,
                  float* __restrict__ state_logits)
{
    __shared__ __align__(16) _Float16 As[NN * ASTR];      // 44 KB A-slice fp16
    __shared__ __align__(16) _Float16 Bs[2 * NKK * 512];  // 20 KB ct-pair B
    __shared__ float redE[NN];
    __shared__ float redN[4][16];
    const int tid  = (int)threadIdx.x;
    const int wv   = tid >> 6;
    const int lane = tid & 63;
    const int lrow = lane & 15;
    const int lgrp = lane >> 4;

    if ((int)blockIdx.x < NODE_BLOCKS) {
        // =================== NODE PATH (round-10/15 body) =================
        const int bid = (int)blockIdx.x;
        const int b   = bid >> 2;
        const int nt  = bid & 3;

        const float* arow = node_attr
            + (size_t)(b * NN + nt * 16 + lrow) * (PP * HH);
        float sm[PP];
#pragma unroll
        for (int p = 0; p < PP; ++p) sm[p] = sim[b * PP + p];

        const f16x8* WH = reinterpret_cast<const f16x8*>(w2_hi);

        f32x4 acc[5] = {{0.f,0.f,0.f,0.f},{0.f,0.f,0.f,0.f},{0.f,0.f,0.f,0.f},
                        {0.f,0.f,0.f,0.f},{0.f,0.f,0.f,0.f}};

#pragma unroll 1
        for (int ch = 0; ch < 4; ++ch) {
            f16x8 a_h[CHK];
#pragma unroll
            for (int q = 0; q < CHK; ++q) {
                const int kk = ch * CHK + q;
                const int h0 = kk * 32 + lgrp * 8;
                float v[8];
                if (kk < NKK2 && h0 + 7 < PP * HH) {
                    f32x4 p0 = *reinterpret_cast<const f32x4*>(arow + h0);
                    f32x4 p1 = *reinterpret_cast<const f32x4*>(arow + h0 + 4);
                    v[0] = p0[0]; v[1] = p0[1]; v[2] = p0[2]; v[3] = p0[3];
                    v[4] = p1[0]; v[5] = p1[1]; v[6] = p1[2]; v[7] = p1[3];
                } else {
#pragma unroll
                    for (int j = 0; j < 8; ++j)
                        v[j] = (kk < NKK2 && h0 + j < PP * HH) ? arow[h0 + j] : 0.f;
                }
#pragma unroll
                for (int j = 0; j < 8; ++j) {
                    const int h = h0 + j;
                    const int p = (h < PP * HH) ? (h / HH) : 0;
                    a_h[q][j] = (_Float16)(v[j] * sm[p]);
                }
            }
#pragma unroll
            for (int q = 0; q < CHK; ++q) {
                const int kk = ch * CHK + q;
                if (kk < NKK2) {
#pragma unroll
                    for (int c = 0; c < 5; ++c) {
                        const int ct = wv + 4 * c;
                        if (ct < NCT) {
                            f16x8 bh = WH[(kk * NCT + ct) * 64 + lane];
                            acc[c] = __builtin_amdgcn_mfma_f32_16x16x32_f16(a_h[q], bh, acc[c], 0, 0, 0);
                        }
                    }
                }
            }
        }

        float rs0 = 0.f, rs1 = 0.f, rs2 = 0.f, rs3 = 0.f;
#pragma unroll
        for (int c = 0; c < 5; ++c) {
            const int ct = wv + 4 * c;
            if (ct < NCT) {
                const int k  = ct * 16 + lrow;
                const bool ok = k < HH;
                const int kc = ok ? k : (HH - 1);
                const float iv  = instr[b * HH + kc];
                const float wsv = ok ? w_state[kc] : 0.f;
                rs0 += eluf(acc[c][0] * iv) * wsv;
                rs1 += eluf(acc[c][1] * iv) * wsv;
                rs2 += eluf(acc[c][2] * iv) * wsv;
                rs3 += eluf(acc[c][3] * iv) * wsv;
            }
        }
#pragma unroll
        for (int msk = 1; msk < 16; msk <<= 1) {
            rs0 += __shfl_xor(rs0, msk);
            rs1 += __shfl_xor(rs1, msk);
            rs2 += __shfl_xor(rs2, msk);
            rs3 += __shfl_xor(rs3, msk);
        }
        if (lrow == 0) {
            redN[wv][lgrp * 4 + 0] = rs0;
            redN[wv][lgrp * 4 + 1] = rs1;
            redN[wv][lgrp * 4 + 2] = rs2;
            redN[wv][lgrp * 4 + 3] = rs3;
        }
        __syncthreads();
        if (tid < 16) {
            const int n = nt * 16 + tid;
            float v = redN[0][tid] + redN[1][tid] + redN[2][tid] + redN[3][tid];
            state_logits[b * NN + n] = v + node_mask[b * NN + n];
        }
        return;
    }

    // ===================== EDGE PATH (coalesced-A round 16) ===============
    const int ebid = (int)blockIdx.x - NODE_BLOCKS;
    const int b    = ebid / NN;
    const int m    = ebid % NN;

    // ---- Stage A: contiguous 76.8 KB slice, coalesced float4 stream ----
    {
        const float* asrc = edge_attr + (size_t)(b * NN + m) * (NN * HH);
        // 19200 floats = 4800 float4; row = q/75, col-quad = q%75
#pragma unroll 1
        for (int q = tid; q < NN * HH / 4; q += 256) {
            f32x4 v = *reinterpret_cast<const f32x4*>(asrc + q * 4);
            const int row = q / 75;
            const int cq  = q - row * 75;
            f16x4 h;
            h[0] = (_Float16)v[0]; h[1] = (_Float16)v[1];
            h[2] = (_Float16)v[2]; h[3] = (_Float16)v[3];
            *reinterpret_cast<f16x4*>(&As[row * ASTR + cq * 4]) = h;
        }
        // zero the pad region h in [300, 320) (fragment reads reach 319)
        f16x4 z = {(_Float16)0.f, (_Float16)0.f, (_Float16)0.f, (_Float16)0.f};
#pragma unroll 1
        for (int i = tid; i < NN * 5; i += 256) {   // 5 quads of 4 per row
            const int row = i / 5;
            const int j   = i - row * 5;
            *reinterpret_cast<f16x4*>(&As[row * ASTR + 300 + j * 4]) = z;
        }
    }
    __syncthreads();

    // ---- A fragments from LDS (once): wave wv owns rows wv*16 + lrow ----
    f16x8 aA[NKK];
    {
        const int arow_l = wv * 16 + lrow;
#pragma unroll
        for (int kk = 0; kk < NKK; ++kk)
            aA[kk] = *reinterpret_cast<const f16x8*>(
                &As[arow_l * ASTR + kk * 32 + lgrp * 8]);
    }

    const f16x8* WH = reinterpret_cast<const f16x8*>(w_hi);
    const int binst = b * HH;

    // ---- B staging ownership (round 12): 20 pair-tiles over 4 waves ----
    const int t0 = wv * 5;
    const f16x8* gp[5];
    int ldst[5];
#pragma unroll
    for (int i = 0; i < 5; ++i) {
        int t  = t0 + i;
        int c  = (t >= NKK) ? 1 : 0;
        int kk = t - c * NKK;
        gp[i]   = WH + ((size_t)kk * NCTE + c) * 64 + lane;
        ldst[i] = (c * NKK + kk) * 512 + lane * 8;
    }

    f16x8 st[5];
#pragma unroll
    for (int i = 0; i < 5; ++i) { st[i] = gp[i][0]; gp[i] += 128; }

    float rs0 = 0.f, rs1 = 0.f, rs2 = 0.f, rs3 = 0.f;

#pragma unroll 1
    for (int p = 0; p < NPAIR; ++p) {
        // write this pair's staged registers into LDS
#pragma unroll
        for (int i = 0; i < 5; ++i)
            *reinterpret_cast<f16x8*>(&Bs[ldst[i]]) = st[i];
        __syncthreads();

        // issue next pair's loads early (consumed after next barrier)
        if (p + 1 < NPAIR) {
#pragma unroll
            for (int i = 0; i < 5; ++i) { st[i] = gp[i][0]; gp[i] += 128; }
        }

        // compute pair from LDS: 2 acc chains of 10 (ct even / ct odd)
        f32x4 acc0 = {0.f, 0.f, 0.f, 0.f};
        f32x4 acc1 = {0.f, 0.f, 0.f, 0.f};
        const _Float16* bsc = &Bs[lane * 8];
#pragma unroll
        for (int kk = 0; kk < NKK; ++kk) {
            f16x8 b0 = *reinterpret_cast<const f16x8*>(bsc + kk * 512);
            f16x8 b1 = *reinterpret_cast<const f16x8*>(bsc + (NKK + kk) * 512);
            acc0 = __builtin_amdgcn_mfma_f32_16x16x32_f16(aA[kk], b0, acc0, 0, 0, 0);
            acc1 = __builtin_amdgcn_mfma_f32_16x16x32_f16(aA[kk], b1, acc1, 0, 0, 0);
        }

        // fused epilogue for both ct's of the pair
#pragma unroll
        for (int c = 0; c < 2; ++c) {
            const int k  = (2 * p + c) * 16 + lrow;
            const bool ok = k < HH;
            const int kc = ok ? k : (HH - 1);
            const float iv = instr[binst + kc];
            const float wr = ok ? w_rel[kc] : 0.f;
            const f32x4 ac = c ? acc1 : acc0;
            rs0 += eluf(ac[0] * iv) * wr;
            rs1 += eluf(ac[1] * iv) * wr;
            rs2 += eluf(ac[2] * iv) * wr;
            rs3 += eluf(ac[3] * iv) * wr;
        }

        __syncthreads();   // all waves done reading Bs before next overwrite
    }

    // reduce over the 16 lanes sharing the same C-rows (masks 1,2,4,8)
#pragma unroll
    for (int msk = 1; msk < 16; msk <<= 1) {
        rs0 += __shfl_xor(rs0, msk);
        rs1 += __shfl_xor(rs1, msk);
        rs2 += __shfl_xor(rs2, msk);
        rs3 += __shfl_xor(rs3, msk);
    }
    if (lrow == 0) {
        const int r0 = wv * 16 + lgrp * 4;
        redE[r0 + 0] = rs0;
        redE[r0 + 1] = rs1;
        redE[r0 + 2] = rs2;
        redE[r0 + 3] = rs3;
    }
    __syncthreads();
    if (tid < 64) {
        float v = redE[tid] * dist[b * NN + tid];
#pragma unroll
        for (int msk = 1; msk < 64; msk <<= 1) v += __shfl_xor(v, msk);
        if (tid == 0)
            rel_logits[b * NN + m] = v + node_mask[b * NN + m];
    }
}

// ---------------------------------------------------------------------------
// Final: softmax both logit sets over n (one wave per b) and blend.
// ---------------------------------------------------------------------------
extern "C" __global__ __launch_bounds__(64)
void final_kernel(const float* __restrict__ rel_logits,
                  const float* __restrict__ state_logits,
                  const float* __restrict__ rel_sim,
                  float* __restrict__ out)
{
    const int b = (int)blockIdx.x;
    const int n = (int)threadIdx.x;
    float sl = state_logits[b * NN + n];
    float rl = rel_logits[b * NN + n];

    float ms = sl, mr = rl;
#pragma unroll
    for (int msk = 1; msk < 64; msk <<= 1) {
        ms = fmaxf(ms, __shfl_xor(ms, msk));
        mr = fmaxf(mr, __shfl_xor(mr, msk));
    }
    float es = __expf(sl - ms);
    float er = __expf(rl - mr);
    float ss = es, sr = er;
#pragma unroll
    for (int msk = 1; msk < 64; msk <<= 1) {
        ss += __shfl_xor(ss, msk);
        sr += __shfl_xor(sr, msk);
    }
    float rr = rel_sim[b];
    out[b * NN + n] = rr * (er / sr) + (1.f - rr) * (es / ss);
}

extern "C" void kernel_launch(void* const* d_in, const int* in_sizes, int n_in,
                              void* d_out, int out_size, void* d_ws, size_t ws_size,
                              hipStream_t stream) {
    const float* node_attr    = (const float*)d_in[0];
    const float* edge_attr    = (const float*)d_in[1];
    const float* instruction  = (const float*)d_in[2];
    const float* distribution = (const float*)d_in[3];
    const float* node_sim     = (const float*)d_in[4];
    const float* rel_sim      = (const float*)d_in[5];
    const float* node_mask    = (const float*)d_in[6];
    const float* w_np         = (const float*)d_in[7];
    const float* w_edge       = (const float*)d_in[8];
    const float* w_state      = (const float*)d_in[9];
    const float* w_rel        = (const float*)d_in[10];
    float* out = (float*)d_out;

    // workspace layout
    float* rel_ws   = (float*)d_ws;                           // [2048] f32
    float* state_ws = rel_ws + BB * NN;                       // [2048] f32
    char*  wsb      = (char*)d_ws;
    const size_t edge_frag = (size_t)NKK * NCTE * 64 * 8 * 2;  // 204,800 B
    _Float16* w_hi  = (_Float16*)(wsb + 16384);
    _Float16* w2_hi = (_Float16*)(wsb + 16384 + edge_frag);

    wprep_kernel<<<dim3(NKK * NCTE + NKK2 * NCT), dim3(64), 0, stream>>>(
        w_edge, w_np, w_hi, w2_hi);

    fused_kernel<<<dim3(NODE_BLOCKS + EDGE_BLOCKS), dim3(256), 0, stream>>>(
        edge_attr, node_attr, instruction, distribution, node_sim, node_mask,
        w_hi, w2_hi, w_rel, w_state, rel_ws, state_ws);

    final_kernel<<<dim3(BB), dim3(64), 0, stream>>>(
        rel_ws, state_ws, rel_sim, out);
}